// Round 6
// baseline (1198.604 us; speedup 1.0000x reference)
//
#include <hip/hip_runtime.h>
#include <math.h>

#define NN 100000
#define NE 1600000
#define ET (NN + NE)
#define D 64
#define EDIM 16
#define BSH 7
#define NB ((NN + 127) >> BSH)  // 782 buckets of 128 nodes

static __device__ __forceinline__ float leaky(float a) { return a >= 0.f ? a : 0.2f * a; }

// monotone float<->uint mapping for atomicMax on floats (handles negatives)
static __device__ __forceinline__ unsigned fmap(float f) {
    unsigned u = __float_as_uint(f);
    return (u & 0x80000000u) ? ~u : (u | 0x80000000u);
}
static __device__ __forceinline__ float funmap(unsigned u) {
    unsigned f = (u & 0x80000000u) ? (u ^ 0x80000000u) : ~u;
    return __uint_as_float(f);
}

// K0: deg[i]=1 (self loop), bucket cursors = 0, clear small scratch, w16[l*16+k]
__global__ __launch_bounds__(256) void k_init(int* __restrict__ deg, int* __restrict__ bcur,
                                              float* __restrict__ meansum,
                                              unsigned* __restrict__ gse_u, unsigned* __restrict__ gsrc_u,
                                              float* __restrict__ w16, const float* __restrict__ We,
                                              const float* __restrict__ ae) {
    int i = blockIdx.x * 256 + threadIdx.x;
    if (i < NN) deg[i] = 1;
    if (i < NB) bcur[i] = 0;
    if (blockIdx.x == 0) {
        int t = threadIdx.x;
        if (t < 16) meansum[t] = 0.f;
        if (t < 3) {
            gse_u[t] = fmap(-3.0e38f);
            gsrc_u[t] = fmap(-3.0e38f);
        }
        if (t < 48) {
            int l = t >> 4, k = t & 15;
            const float* wr = We + l * (EDIM * D) + k * D;
            const float* av = ae + l * D;
            float s = 0.f;
#pragma unroll
            for (int j = 0; j < D; j++) s += wr[j] * av[j];
            w16[t] = s;
        }
    }
}

// K1: rank of dst (atomic histogram), record {src,se0,se1,se2}, packed (d,rank),
// edge_attr column sums, global max of edge scores
__global__ __launch_bounds__(256) void k_edge(const int* __restrict__ ei, const float* __restrict__ ea,
                                              const float* __restrict__ w16, int* __restrict__ deg,
                                              unsigned* __restrict__ pack,
                                              float4* __restrict__ rec4, float* __restrict__ meansum,
                                              unsigned* __restrict__ gse_u) {
    int tid = blockIdx.x * blockDim.x + threadIdx.x;
    int stride = gridDim.x * blockDim.x;
    float wr[48];
#pragma unroll
    for (int c = 0; c < 48; c++) wr[c] = w16[c];
    float ms[16];
#pragma unroll
    for (int c = 0; c < 16; c++) ms[c] = 0.f;
    float smax[3] = {-3e38f, -3e38f, -3e38f};
    for (int e = tid; e < NE; e += stride) {
        int s = ei[e];
        int d = ei[NE + e];
        unsigned rank = (unsigned)atomicAdd(&deg[d], 1);  // >=1; rank 0 is the self loop
        pack[e] = ((unsigned)d << 15) | rank;             // d<2^17, rank<2^15
        const float4* ea4 = (const float4*)(ea + (size_t)e * EDIM);
        float4 v0 = ea4[0], v1 = ea4[1], v2 = ea4[2], v3 = ea4[3];
        float vv[16] = {v0.x, v0.y, v0.z, v0.w, v1.x, v1.y, v1.z, v1.w,
                        v2.x, v2.y, v2.z, v2.w, v3.x, v3.y, v3.z, v3.w};
#pragma unroll
        for (int c = 0; c < 16; c++) ms[c] += vv[c];
        float sl[3];
#pragma unroll
        for (int l = 0; l < 3; l++) {
            float sv = 0.f;
#pragma unroll
            for (int c = 0; c < 16; c++) sv = fmaf(vv[c], wr[l * 16 + c], sv);
            sl[l] = sv;
            smax[l] = fmaxf(smax[l], sv);
        }
        rec4[e] = make_float4(__int_as_float(s), sl[0], sl[1], sl[2]);
    }
#pragma unroll
    for (int c = 0; c < 16; c++)
        for (int o = 32; o; o >>= 1) ms[c] += __shfl_xor(ms[c], o);
#pragma unroll
    for (int l = 0; l < 3; l++)
        for (int o = 32; o; o >>= 1) smax[l] = fmaxf(smax[l], __shfl_xor(smax[l], o));
    __shared__ float bsum[16];
    __shared__ unsigned bmax[3];
    if (threadIdx.x < 16) bsum[threadIdx.x] = 0.f;
    if (threadIdx.x < 3) bmax[threadIdx.x] = fmap(-3e38f);
    __syncthreads();
    if ((threadIdx.x & 63) == 0) {
        for (int c = 0; c < 16; c++) atomicAdd(&bsum[c], ms[c]);
        for (int l = 0; l < 3; l++) atomicMax(&bmax[l], fmap(smax[l]));
    }
    __syncthreads();
    if (threadIdx.x < 16) atomicAdd(&meansum[threadIdx.x], bsum[threadIdx.x]);
    if (threadIdx.x < 3) atomicMax(&gse_u[threadIdx.x], bmax[threadIdx.x]);
}

// K2a: per-block exclusive scan of deg
__global__ __launch_bounds__(256) void k_scan1(const int* __restrict__ deg, int* __restrict__ rowstart,
                                               int* __restrict__ blocksum) {
    __shared__ int sd[256];
    int t = threadIdx.x;
    int i = blockIdx.x * 256 + t;
    int v = (i < NN) ? deg[i] : 0;
    sd[t] = v;
    __syncthreads();
    for (int o = 1; o < 256; o <<= 1) {
        int x = sd[t];
        int y = (t >= o) ? sd[t - o] : 0;
        __syncthreads();
        sd[t] = x + y;
        __syncthreads();
    }
    int incl = sd[t];
    if (i < NN) rowstart[i] = incl - v;
    if (t == 255) blocksum[blockIdx.x] = incl;
}

// K2b: scan block sums; finalize self-loop scores slw[l] and gse_f[l]
__global__ __launch_bounds__(512) void k_scan2(const int* __restrict__ blocksum, int* __restrict__ blockoff,
                                               int* __restrict__ rowstart, const float* __restrict__ meansum,
                                               const float* __restrict__ w16, float* __restrict__ slw,
                                               const unsigned* __restrict__ gse_u, float* __restrict__ gse_f,
                                               int nb) {
    __shared__ int sd[512];
    int t = threadIdx.x;
    int v = (t < nb) ? blocksum[t] : 0;
    sd[t] = v;
    __syncthreads();
    for (int o = 1; o < 512; o <<= 1) {
        int x = sd[t];
        int y = (t >= o) ? sd[t - o] : 0;
        __syncthreads();
        sd[t] = x + y;
        __syncthreads();
    }
    if (t < nb) blockoff[t] = sd[t] - v;
    if (t == 0) rowstart[NN] = ET;
    if (t < 3) {
        float s = 0.f;
        for (int k = 0; k < 16; k++) s += (meansum[k] * (1.0f / NE)) * w16[t * 16 + k];
        slw[t] = s;
        gse_f[t] = fmaxf(funmap(gse_u[t]), s);
    }
}

// K2c: add block offsets
__global__ __launch_bounds__(256) void k_scan3(int* __restrict__ rowstart, const int* __restrict__ blockoff) {
    int i = blockIdx.x * 256 + threadIdx.x;
    if (i < NN) rowstart[i] = rowstart[i] + blockoff[i >> 8];
}

// K3a: bucket-append records (dense writes); final pos carried alongside
__global__ __launch_bounds__(256) void k_scatA(const float4* __restrict__ rec4,
                                               const unsigned* __restrict__ pack,
                                               const float* __restrict__ slw,
                                               const int* __restrict__ rowstart,
                                               int* __restrict__ bcur,
                                               float4* __restrict__ st4, int* __restrict__ stpos) {
    int tid = blockIdx.x * blockDim.x + threadIdx.x;
    int stride = gridDim.x * blockDim.x;
    float s0 = slw[0], s1 = slw[1], s2 = slw[2];
    for (int e = tid; e < ET; e += stride) {
        float4 rec;
        int d, rank;
        if (e < NE) {
            rec = rec4[e];
            unsigned p = pack[e];
            d = (int)(p >> 15);
            rank = (int)(p & 32767u);
        } else {
            d = e - NE;
            rank = 0;
            rec = make_float4(__int_as_float(d), s0, s1, s2);
        }
        int pos = rowstart[d] + rank;
        int bb = rowstart[d & ~127];  // bucket base (capacity exact by construction)
        int c = atomicAdd(&bcur[d >> BSH], 1);
        st4[bb + c] = rec;
        stpos[bb + c] = pos;
    }
}

// K3b: one block per bucket; scatter within L2-resident CSR window
__global__ __launch_bounds__(256) void k_scatB(const float4* __restrict__ st4,
                                               const int* __restrict__ stpos,
                                               const int* __restrict__ rowstart,
                                               float4* __restrict__ csr) {
    int b = blockIdx.x;
    int lo = rowstart[b << BSH];
    int hi = (b == NB - 1) ? ET : rowstart[(b + 1) << BSH];
    for (int i = lo + threadIdx.x; i < hi; i += 256) {
        csr[stpos[i]] = st4[i];
    }
}

// GEMM: h = x @ W (+ s_src, s_dst per row, + global max of s_src). lane = output column.
__global__ __launch_bounds__(256) void k_gemm(const float* __restrict__ x, const float* __restrict__ W,
                                              const float* __restrict__ asrc, const float* __restrict__ adst,
                                              float* __restrict__ h, float* __restrict__ ssrc,
                                              float* __restrict__ sdst, unsigned* __restrict__ gsrcu) {
    int t = threadIdx.x;
    int lane = t & 63;
    int wv = __builtin_amdgcn_readfirstlane(t >> 6);
    int row0 = blockIdx.x * 64 + wv * 16;
    float Wreg[64];
#pragma unroll
    for (int k = 0; k < 64; k++) Wreg[k] = W[k * 64 + lane];
    float asl = asrc[lane], adl = adst[lane];
    float wmax = -3e38f;
    for (int rr = 0; rr < 16; rr++) {
        int r = row0 + rr;
        if (r >= NN) break;
        const float* xr = x + (size_t)r * 64;
        float acc = 0.f;
#pragma unroll
        for (int k = 0; k < 64; k++) acc = fmaf(xr[k], Wreg[k], acc);
        h[(size_t)r * 64 + lane] = acc;
        float ps = acc * asl, pd = acc * adl;
#pragma unroll
        for (int o = 32; o; o >>= 1) {
            ps += __shfl_xor(ps, o);
            pd += __shfl_xor(pd, o);
        }
        wmax = fmaxf(wmax, ps);
        if (lane == 0) {
            ssrc[r] = ps;
            sdst[r] = pd;
        }
    }
    if (lane == 0) atomicMax(gsrcu, fmap(wmax));
}

// Aggregation: single pass, safe global softmax bound M (bias cancels in e/z).
// Phase S: lane=edge computes ew. Phase P: 4 edges/step, 16 lanes/edge, float4 h-slices.
template <int LAYER>
__global__ __launch_bounds__(256) void k_agg(const float4* __restrict__ csr, const int* __restrict__ rowstart,
                                             const float* __restrict__ ssrc, const float* __restrict__ sdst,
                                             const float* __restrict__ h, const float* __restrict__ bias,
                                             const unsigned* __restrict__ gsrcu, const float* __restrict__ gsef,
                                             float* __restrict__ out) {
    int t = threadIdx.x;
    int lane = t & 63;
    int wv = __builtin_amdgcn_readfirstlane(t >> 6);
    int n = blockIdx.x * 4 + wv;  // NN % 4 == 0, always valid
    int start = rowstart[n];
    int dg = rowstart[n + 1] - start;
    float sd = sdst[n];
    float M = leaky(funmap(gsrcu[0]) + sd + gsef[LAYER]);
    int g = lane >> 4;             // edge-slot group 0..3
    int fslice = (lane & 15) * 4;  // this lane's 4-feature slice
    float4 acc = make_float4(0.f, 0.f, 0.f, 0.f);
    float z = 0.f;
    for (int base = 0; base < dg; base += 64) {
        int i = base + lane;
        float ew = 0.f;
        int es = 0;
        if (i < dg) {
            float4 rec = csr[start + i];
            float se = (LAYER == 0) ? rec.y : ((LAYER == 1) ? rec.z : rec.w);
            es = __float_as_int(rec.x);
            ew = __expf(leaky(ssrc[es] + sd + se) - M);
        }
        z += ew;
        int cnt = min(64, dg - base);
#pragma unroll 4
        for (int js = 0; js < cnt; js += 4) {
            int j = js + g;                    // <= 63; tail slots have ew==0, es==0 (harmless h[0] load)
            float wj = __shfl(ew, j);
            int sj = __shfl(es, j);
            float4 hv = *(const float4*)(h + (size_t)sj * 64 + fslice);
            acc.x = fmaf(wj, hv.x, acc.x);
            acc.y = fmaf(wj, hv.y, acc.y);
            acc.z = fmaf(wj, hv.z, acc.z);
            acc.w = fmaf(wj, hv.w, acc.w);
        }
    }
    // reduce acc across the 4 groups; z across all 64 lanes
#pragma unroll
    for (int o = 16; o <= 32; o <<= 1) {
        acc.x += __shfl_xor(acc.x, o);
        acc.y += __shfl_xor(acc.y, o);
        acc.z += __shfl_xor(acc.z, o);
        acc.w += __shfl_xor(acc.w, o);
    }
#pragma unroll
    for (int o = 32; o; o >>= 1) z += __shfl_xor(z, o);
    if (lane < 16) {
        float inv = 1.f / z;
        float4 bv = *(const float4*)(bias + fslice);
        float4 v;
        v.x = acc.x * inv + bv.x;
        v.y = acc.y * inv + bv.y;
        v.z = acc.z * inv + bv.z;
        v.w = acc.w * inv + bv.w;
        const float k = 0.70710678118654752f;
        v.x = 0.5f * v.x * (1.0f + erff(v.x * k));
        v.y = 0.5f * v.y * (1.0f + erff(v.y * k));
        v.z = 0.5f * v.z * (1.0f + erff(v.z * k));
        v.w = 0.5f * v.w * (1.0f + erff(v.w * k));
        *(float4*)(out + (size_t)n * 64 + fslice) = v;
    }
}

extern "C" void kernel_launch(void* const* d_in, const int* in_sizes, int n_in,
                              void* d_out, int out_size, void* d_ws, size_t ws_size,
                              hipStream_t stream) {
    const float* x0 = (const float*)d_in[0];
    const int* ei = (const int*)d_in[1];
    const float* ea = (const float*)d_in[2];
    const float* Ws = (const float*)d_in[3];
    const float* asrc = (const float*)d_in[4];
    const float* adst = (const float*)d_in[5];
    const float* We = (const float*)d_in[6];
    const float* ae = (const float*)d_in[7];
    const float* bias = (const float*)d_in[8];

    char* wsb = (char*)d_ws;
    size_t off = 0;
    auto alloc = [&](size_t bytes) -> char* {
        char* p = wsb + off;
        off += (bytes + 255) & ~(size_t)255;
        return p;
    };
    float* xA = (float*)alloc((size_t)NN * D * 4);  // also staging st4 (scat phase only)
    float* xB = (float*)alloc((size_t)NN * D * 4);  // staging spill continues here
    float* h = (float*)alloc((size_t)NN * D * 4);
    float* ssrc = (float*)alloc((size_t)NN * 4);
    float* sdst = (float*)alloc((size_t)NN * 4);
    float4* rec4 = (float4*)alloc((size_t)NE * 16);
    float4* csr = (float4*)alloc((size_t)ET * 16);
    unsigned* pack = (unsigned*)alloc((size_t)NE * 4);
    int* deg = (int*)alloc((size_t)NN * 4);
    int* rowstart = (int*)alloc((size_t)(NN + 1) * 4);
    int* blocksum = (int*)alloc(512 * 4);
    int* blockoff = (int*)alloc(512 * 4);
    float* meansum = (float*)alloc(16 * 4);
    float* w16 = (float*)alloc(48 * 4);
    float* slw = (float*)alloc(3 * 4);
    unsigned* gse_u = (unsigned*)alloc(3 * 4);
    float* gse_f = (float*)alloc(3 * 4);
    unsigned* gsrc_u = (unsigned*)alloc(3 * 4);
    int* bcur = (int*)alloc((size_t)NB * 4);
    // staging aliases xA..xB (51.2 MB >= 34 MB needed); dead before first gemm/agg write.
    // st4 = ET*16 B = 27.2 MB from xA; stpos starts at byte offset ET*16 (= xA + 4*ET floats).
    float4* st4 = (float4*)xA;
    int* stpos = (int*)(xA + 4 * (size_t)ET);

    int nb = (NN + 255) / 256;  // 391
    k_init<<<nb, 256, 0, stream>>>(deg, bcur, meansum, gse_u, gsrc_u, w16, We, ae);
    k_edge<<<1024, 256, 0, stream>>>(ei, ea, w16, deg, pack, rec4, meansum, gse_u);
    k_scan1<<<nb, 256, 0, stream>>>(deg, rowstart, blocksum);
    k_scan2<<<1, 512, 0, stream>>>(blocksum, blockoff, rowstart, meansum, w16, slw, gse_u, gse_f, nb);
    k_scan3<<<nb, 256, 0, stream>>>(rowstart, blockoff);
    k_scatA<<<2048, 256, 0, stream>>>(rec4, pack, slw, rowstart, bcur, st4, stpos);
    k_scatB<<<NB, 256, 0, stream>>>(st4, stpos, rowstart, csr);

    float* outp = (float*)d_out;
    int gg = (NN + 63) / 64;
    // layer 0
    k_gemm<<<gg, 256, 0, stream>>>(x0, Ws, asrc, adst, h, ssrc, sdst, gsrc_u + 0);
    k_agg<0><<<NN / 4, 256, 0, stream>>>(csr, rowstart, ssrc, sdst, h, bias, gsrc_u + 0, gse_f, xA);
    // layer 1
    k_gemm<<<gg, 256, 0, stream>>>(xA, Ws + 4096, asrc + 64, adst + 64, h, ssrc, sdst, gsrc_u + 1);
    k_agg<1><<<NN / 4, 256, 0, stream>>>(csr, rowstart, ssrc, sdst, h, bias + 64, gsrc_u + 1, gse_f, xB);
    // layer 2
    k_gemm<<<gg, 256, 0, stream>>>(xB, Ws + 8192, asrc + 128, adst + 128, h, ssrc, sdst, gsrc_u + 2);
    k_agg<2><<<NN / 4, 256, 0, stream>>>(csr, rowstart, ssrc, sdst, h, bias + 128, gsrc_u + 2, gse_f, outp);
}

// Round 8
// 791.477 us; speedup vs baseline: 1.5144x; 1.5144x over previous
//
#include <hip/hip_runtime.h>
#include <math.h>

#define NN 100000
#define NE 1600000
#define ET (NN + NE)
#define D 64
#define EDIM 16

static __device__ __forceinline__ float leaky(float a) { return a >= 0.f ? a : 0.2f * a; }

// monotone float<->uint mapping for atomicMax on floats (handles negatives)
static __device__ __forceinline__ unsigned fmap(float f) {
    unsigned u = __float_as_uint(f);
    return (u & 0x80000000u) ? ~u : (u | 0x80000000u);
}
static __device__ __forceinline__ float funmap(unsigned u) {
    unsigned f = (u & 0x80000000u) ? (u ^ 0x80000000u) : ~u;
    return __uint_as_float(f);
}

// K0: deg[i]=1 (self loop), clear small scratch, block0 computes w16[l*16+k]
__global__ __launch_bounds__(256) void k_init(int* __restrict__ deg, float* __restrict__ meansum,
                                              unsigned* __restrict__ gse_u, unsigned* __restrict__ gsrc_u,
                                              float* __restrict__ w16, const float* __restrict__ We,
                                              const float* __restrict__ ae) {
    int i = blockIdx.x * 256 + threadIdx.x;
    if (i < NN) deg[i] = 1;
    if (blockIdx.x == 0) {
        int t = threadIdx.x;
        if (t < 16) meansum[t] = 0.f;
        if (t < 3) {
            gse_u[t] = fmap(-3.0e38f);
            gsrc_u[t] = fmap(-3.0e38f);
        }
        if (t < 48) {
            int l = t >> 4, k = t & 15;
            const float* wr = We + l * (EDIM * D) + k * D;
            const float* av = ae + l * D;
            float s = 0.f;
#pragma unroll
            for (int j = 0; j < D; j++) s += wr[j] * av[j];
            w16[t] = s;
        }
    }
}

// K1: rank of dst (atomic histogram), record {src,se0,se1,se2}, packed (d,rank),
// edge_attr column sums, global max of edge scores
__global__ __launch_bounds__(256) void k_edge(const int* __restrict__ ei, const float* __restrict__ ea,
                                              const float* __restrict__ w16, int* __restrict__ deg,
                                              unsigned* __restrict__ pack,
                                              float4* __restrict__ rec4, float* __restrict__ meansum,
                                              unsigned* __restrict__ gse_u) {
    int tid = blockIdx.x * blockDim.x + threadIdx.x;
    int stride = gridDim.x * blockDim.x;
    float wr[48];
#pragma unroll
    for (int c = 0; c < 48; c++) wr[c] = w16[c];
    float ms[16];
#pragma unroll
    for (int c = 0; c < 16; c++) ms[c] = 0.f;
    float smax[3] = {-3e38f, -3e38f, -3e38f};
    for (int e = tid; e < NE; e += stride) {
        int s = ei[e];
        int d = ei[NE + e];
        unsigned rank = (unsigned)atomicAdd(&deg[d], 1);  // >=1; rank 0 is the self loop
        pack[e] = ((unsigned)d << 15) | rank;             // d<2^17, rank<2^15
        const float4* ea4 = (const float4*)(ea + (size_t)e * EDIM);
        float4 v0 = ea4[0], v1 = ea4[1], v2 = ea4[2], v3 = ea4[3];
        float vv[16] = {v0.x, v0.y, v0.z, v0.w, v1.x, v1.y, v1.z, v1.w,
                        v2.x, v2.y, v2.z, v2.w, v3.x, v3.y, v3.z, v3.w};
#pragma unroll
        for (int c = 0; c < 16; c++) ms[c] += vv[c];
        float sl[3];
#pragma unroll
        for (int l = 0; l < 3; l++) {
            float sv = 0.f;
#pragma unroll
            for (int c = 0; c < 16; c++) sv = fmaf(vv[c], wr[l * 16 + c], sv);
            sl[l] = sv;
            smax[l] = fmaxf(smax[l], sv);
        }
        rec4[e] = make_float4(__int_as_float(s), sl[0], sl[1], sl[2]);
    }
#pragma unroll
    for (int c = 0; c < 16; c++)
        for (int o = 32; o; o >>= 1) ms[c] += __shfl_xor(ms[c], o);
#pragma unroll
    for (int l = 0; l < 3; l++)
        for (int o = 32; o; o >>= 1) smax[l] = fmaxf(smax[l], __shfl_xor(smax[l], o));
    __shared__ float bsum[16];
    __shared__ unsigned bmax[3];
    if (threadIdx.x < 16) bsum[threadIdx.x] = 0.f;
    if (threadIdx.x < 3) bmax[threadIdx.x] = fmap(-3e38f);
    __syncthreads();
    if ((threadIdx.x & 63) == 0) {
        for (int c = 0; c < 16; c++) atomicAdd(&bsum[c], ms[c]);
        for (int l = 0; l < 3; l++) atomicMax(&bmax[l], fmap(smax[l]));
    }
    __syncthreads();
    if (threadIdx.x < 16) atomicAdd(&meansum[threadIdx.x], bsum[threadIdx.x]);
    if (threadIdx.x < 3) atomicMax(&gse_u[threadIdx.x], bmax[threadIdx.x]);
}

// K2a: per-block exclusive scan of deg
__global__ __launch_bounds__(256) void k_scan1(const int* __restrict__ deg, int* __restrict__ rowstart,
                                               int* __restrict__ blocksum) {
    __shared__ int sd[256];
    int t = threadIdx.x;
    int i = blockIdx.x * 256 + t;
    int v = (i < NN) ? deg[i] : 0;
    sd[t] = v;
    __syncthreads();
    for (int o = 1; o < 256; o <<= 1) {
        int x = sd[t];
        int y = (t >= o) ? sd[t - o] : 0;
        __syncthreads();
        sd[t] = x + y;
        __syncthreads();
    }
    int incl = sd[t];
    if (i < NN) rowstart[i] = incl - v;
    if (t == 255) blocksum[blockIdx.x] = incl;
}

// K2b: scan block sums; finalize self-loop scores slw[l] and gse_f[l]
__global__ __launch_bounds__(512) void k_scan2(const int* __restrict__ blocksum, int* __restrict__ blockoff,
                                               int* __restrict__ rowstart, const float* __restrict__ meansum,
                                               const float* __restrict__ w16, float* __restrict__ slw,
                                               const unsigned* __restrict__ gse_u, float* __restrict__ gse_f,
                                               int nb) {
    __shared__ int sd[512];
    int t = threadIdx.x;
    int v = (t < nb) ? blocksum[t] : 0;
    sd[t] = v;
    __syncthreads();
    for (int o = 1; o < 512; o <<= 1) {
        int x = sd[t];
        int y = (t >= o) ? sd[t - o] : 0;
        __syncthreads();
        sd[t] = x + y;
        __syncthreads();
    }
    if (t < nb) blockoff[t] = sd[t] - v;
    if (t == 0) rowstart[NN] = ET;
    if (t < 3) {
        float s = 0.f;
        for (int k = 0; k < 16; k++) s += (meansum[k] * (1.0f / NE)) * w16[t * 16 + k];
        slw[t] = s;
        gse_f[t] = fmaxf(funmap(gse_u[t]), s);
    }
}

// K2c: add block offsets
__global__ __launch_bounds__(256) void k_scan3(int* __restrict__ rowstart, const int* __restrict__ blockoff) {
    int i = blockIdx.x * 256 + threadIdx.x;
    if (i < NN) rowstart[i] = rowstart[i] + blockoff[i >> 8];
}

// K3a: inverse permutation — inv[pos] = e. Random 4B scatter into 6.8MB (L2-absorbed), no atomics.
__global__ __launch_bounds__(256) void k_scat1(const unsigned* __restrict__ pack,
                                               const int* __restrict__ rowstart,
                                               int* __restrict__ inv) {
    int tid = blockIdx.x * blockDim.x + threadIdx.x;
    int stride = gridDim.x * blockDim.x;
    for (int e = tid; e < ET; e += stride) {
        int d, rank;
        if (e < NE) {
            unsigned p = pack[e];
            d = (int)(p >> 15);
            rank = (int)(p & 32767u);
        } else {
            d = e - NE;
            rank = 0;
        }
        inv[rowstart[d] + rank] = e;
    }
}

// K3b: csr[pos] = rec(inv[pos]) — sequential (coalesced) CSR write; random READS of L3-resident rec4.
__global__ __launch_bounds__(256) void k_scat2(const int* __restrict__ inv,
                                               const float4* __restrict__ rec4,
                                               const float* __restrict__ slw,
                                               float4* __restrict__ csr) {
    int tid = blockIdx.x * blockDim.x + threadIdx.x;
    int stride = gridDim.x * blockDim.x;
    float s0 = slw[0], s1 = slw[1], s2 = slw[2];
    for (int pos = tid; pos < ET; pos += stride) {
        int e = inv[pos];
        float4 rec;
        if (e < NE) {
            rec = rec4[e];
        } else {
            rec = make_float4(__int_as_float(e - NE), s0, s1, s2);
        }
        csr[pos] = rec;
    }
}

// GEMM: h = x @ W (+ s_src, s_dst per row, + global max of s_src). lane = output column.
__global__ __launch_bounds__(256) void k_gemm(const float* __restrict__ x, const float* __restrict__ W,
                                              const float* __restrict__ asrc, const float* __restrict__ adst,
                                              float* __restrict__ h, float* __restrict__ ssrc,
                                              float* __restrict__ sdst, unsigned* __restrict__ gsrcu) {
    int t = threadIdx.x;
    int lane = t & 63;
    int wv = __builtin_amdgcn_readfirstlane(t >> 6);
    int row0 = blockIdx.x * 64 + wv * 16;
    float Wreg[64];
#pragma unroll
    for (int k = 0; k < 64; k++) Wreg[k] = W[k * 64 + lane];
    float asl = asrc[lane], adl = adst[lane];
    float wmax = -3e38f;
    for (int rr = 0; rr < 16; rr++) {
        int r = row0 + rr;
        if (r >= NN) break;
        const float* xr = x + (size_t)r * 64;
        float acc = 0.f;
#pragma unroll
        for (int k = 0; k < 64; k++) acc = fmaf(xr[k], Wreg[k], acc);
        h[(size_t)r * 64 + lane] = acc;
        float ps = acc * asl, pd = acc * adl;
#pragma unroll
        for (int o = 32; o; o >>= 1) {
            ps += __shfl_xor(ps, o);
            pd += __shfl_xor(pd, o);
        }
        wmax = fmaxf(wmax, ps);
        if (lane == 0) {
            ssrc[r] = ps;
            sdst[r] = pd;
        }
    }
    if (lane == 0) atomicMax(gsrcu, fmap(wmax));
}

// Aggregation: single pass, safe global softmax bound M (bias cancels in e/z).
// Phase S: lane=edge computes ew. Phase P: 4 edges/step, 16 lanes/edge, float4 h-slices.
template <int LAYER>
__global__ __launch_bounds__(256) void k_agg(const float4* __restrict__ csr, const int* __restrict__ rowstart,
                                             const float* __restrict__ ssrc, const float* __restrict__ sdst,
                                             const float* __restrict__ h, const float* __restrict__ bias,
                                             const unsigned* __restrict__ gsrcu, const float* __restrict__ gsef,
                                             float* __restrict__ out) {
    int t = threadIdx.x;
    int lane = t & 63;
    int wv = __builtin_amdgcn_readfirstlane(t >> 6);
    int n = blockIdx.x * 4 + wv;  // NN % 4 == 0, always valid
    int start = rowstart[n];
    int dg = rowstart[n + 1] - start;
    float sd = sdst[n];
    float M = leaky(funmap(gsrcu[0]) + sd + gsef[LAYER]);
    int g = lane >> 4;             // edge-slot group 0..3
    int fslice = (lane & 15) * 4;  // this lane's 4-feature slice
    float4 acc = make_float4(0.f, 0.f, 0.f, 0.f);
    float z = 0.f;
    for (int base = 0; base < dg; base += 64) {
        int i = base + lane;
        float ew = 0.f;
        int es = 0;
        if (i < dg) {
            float4 rec = csr[start + i];
            float se = (LAYER == 0) ? rec.y : ((LAYER == 1) ? rec.z : rec.w);
            es = __float_as_int(rec.x);
            ew = __expf(leaky(ssrc[es] + sd + se) - M);
        }
        z += ew;
        int cnt = min(64, dg - base);
#pragma unroll 4
        for (int js = 0; js < cnt; js += 4) {
            int j = js + g;                    // <= 63; tail slots have ew==0, es==0 (harmless h[0] load)
            float wj = __shfl(ew, j);
            int sj = __shfl(es, j);
            float4 hv = *(const float4*)(h + (size_t)sj * 64 + fslice);
            acc.x = fmaf(wj, hv.x, acc.x);
            acc.y = fmaf(wj, hv.y, acc.y);
            acc.z = fmaf(wj, hv.z, acc.z);
            acc.w = fmaf(wj, hv.w, acc.w);
        }
    }
    // reduce acc across the 4 groups; z across all 64 lanes
#pragma unroll
    for (int o = 16; o <= 32; o <<= 1) {
        acc.x += __shfl_xor(acc.x, o);
        acc.y += __shfl_xor(acc.y, o);
        acc.z += __shfl_xor(acc.z, o);
        acc.w += __shfl_xor(acc.w, o);
    }
#pragma unroll
    for (int o = 32; o; o >>= 1) z += __shfl_xor(z, o);
    if (lane < 16) {
        float inv = 1.f / z;
        float4 bv = *(const float4*)(bias + fslice);
        float4 v;
        v.x = acc.x * inv + bv.x;
        v.y = acc.y * inv + bv.y;
        v.z = acc.z * inv + bv.z;
        v.w = acc.w * inv + bv.w;
        const float k = 0.70710678118654752f;
        v.x = 0.5f * v.x * (1.0f + erff(v.x * k));
        v.y = 0.5f * v.y * (1.0f + erff(v.y * k));
        v.z = 0.5f * v.z * (1.0f + erff(v.z * k));
        v.w = 0.5f * v.w * (1.0f + erff(v.w * k));
        *(float4*)(out + (size_t)n * 64 + fslice) = v;
    }
}

extern "C" void kernel_launch(void* const* d_in, const int* in_sizes, int n_in,
                              void* d_out, int out_size, void* d_ws, size_t ws_size,
                              hipStream_t stream) {
    const float* x0 = (const float*)d_in[0];
    const int* ei = (const int*)d_in[1];
    const float* ea = (const float*)d_in[2];
    const float* Ws = (const float*)d_in[3];
    const float* asrc = (const float*)d_in[4];
    const float* adst = (const float*)d_in[5];
    const float* We = (const float*)d_in[6];
    const float* ae = (const float*)d_in[7];
    const float* bias = (const float*)d_in[8];

    char* wsb = (char*)d_ws;
    size_t off = 0;
    auto alloc = [&](size_t bytes) -> char* {
        char* p = wsb + off;
        off += (bytes + 255) & ~(size_t)255;
        return p;
    };
    float* xA = (float*)alloc((size_t)NN * D * 4);
    float* xB = (float*)alloc((size_t)NN * D * 4);
    float* h = (float*)alloc((size_t)NN * D * 4);
    float* ssrc = (float*)alloc((size_t)NN * 4);
    float* sdst = (float*)alloc((size_t)NN * 4);
    float4* rec4 = (float4*)alloc((size_t)NE * 16);
    float4* csr = (float4*)alloc((size_t)ET * 16);
    unsigned* pack = (unsigned*)alloc((size_t)NE * 4);
    int* inv = (int*)alloc((size_t)ET * 4);
    int* deg = (int*)alloc((size_t)NN * 4);
    int* rowstart = (int*)alloc((size_t)(NN + 1) * 4);
    int* blocksum = (int*)alloc(512 * 4);
    int* blockoff = (int*)alloc(512 * 4);
    float* meansum = (float*)alloc(16 * 4);
    float* w16 = (float*)alloc(48 * 4);
    float* slw = (float*)alloc(3 * 4);
    unsigned* gse_u = (unsigned*)alloc(3 * 4);
    float* gse_f = (float*)alloc(3 * 4);
    unsigned* gsrc_u = (unsigned*)alloc(3 * 4);

    int nb = (NN + 255) / 256;  // 391
    k_init<<<nb, 256, 0, stream>>>(deg, meansum, gse_u, gsrc_u, w16, We, ae);
    k_edge<<<1024, 256, 0, stream>>>(ei, ea, w16, deg, pack, rec4, meansum, gse_u);
    k_scan1<<<nb, 256, 0, stream>>>(deg, rowstart, blocksum);
    k_scan2<<<1, 512, 0, stream>>>(blocksum, blockoff, rowstart, meansum, w16, slw, gse_u, gse_f, nb);
    k_scan3<<<nb, 256, 0, stream>>>(rowstart, blockoff);
    k_scat1<<<2048, 256, 0, stream>>>(pack, rowstart, inv);
    k_scat2<<<2048, 256, 0, stream>>>(inv, rec4, slw, csr);

    float* outp = (float*)d_out;
    int gg = (NN + 63) / 64;
    // layer 0
    k_gemm<<<gg, 256, 0, stream>>>(x0, Ws, asrc, adst, h, ssrc, sdst, gsrc_u + 0);
    k_agg<0><<<NN / 4, 256, 0, stream>>>(csr, rowstart, ssrc, sdst, h, bias, gsrc_u + 0, gse_f, xA);
    // layer 1
    k_gemm<<<gg, 256, 0, stream>>>(xA, Ws + 4096, asrc + 64, adst + 64, h, ssrc, sdst, gsrc_u + 1);
    k_agg<1><<<NN / 4, 256, 0, stream>>>(csr, rowstart, ssrc, sdst, h, bias + 64, gsrc_u + 1, gse_f, xB);
    // layer 2
    k_gemm<<<gg, 256, 0, stream>>>(xB, Ws + 8192, asrc + 128, adst + 128, h, ssrc, sdst, gsrc_u + 2);
    k_agg<2><<<NN / 4, 256, 0, stream>>>(csr, rowstart, ssrc, sdst, h, bias + 128, gsrc_u + 2, gse_f, outp);
}